// Round 6
// baseline (7440.427 us; speedup 1.0000x reference)
//
#include <hip/hip_runtime.h>
#include <hip/hip_bf16.h>

// LSTM: B=64, S=512, D=512, H=1024, L=2, O=256
// Persistent kernel, fence-FREE cross-XCD coherence:
//   h stores/loads use sc0 sc1 (Infinity-Cache coherent), barrier = relaxed atomics only.
// 256 WGs (128/layer, 8 h-cols each), weights held in VGPRs via volatile-asm loads,
// c-state in registers.  waves_per_eu(1,1) -> 512-VGPR budget, no spill.

namespace {
constexpr int Bn = 64, Sn = 512, Dn = 512, Hn = 1024, On = 256;
constexpr int BH = Bn * Hn;  // 65536
}

typedef unsigned short u16;
typedef unsigned int u32;
typedef float f32x4 __attribute__((ext_vector_type(4)));
typedef short s16x8 __attribute__((ext_vector_type(8)));

__device__ __forceinline__ u16 f2bf(float f) {
    unsigned int u = __float_as_uint(f);
    unsigned int r = (u + 0x7fffu + ((u >> 16) & 1u)) >> 16;
    return (u16)r;
}
__device__ __forceinline__ float bf2f(u16 b) {
    return __uint_as_float(((unsigned int)b) << 16);
}
__device__ __forceinline__ float sigmf(float x) { return 1.0f / (1.0f + __expf(-x)); }

__device__ __forceinline__ s16x8 cvt8(const float4 a, const float4 b) {
    s16x8 v;
    v[0] = (short)f2bf(a.x); v[1] = (short)f2bf(a.y); v[2] = (short)f2bf(a.z); v[3] = (short)f2bf(a.w);
    v[4] = (short)f2bf(b.x); v[5] = (short)f2bf(b.y); v[6] = (short)f2bf(b.z); v[7] = (short)f2bf(b.w);
    return v;
}

// ---- coherent (Infinity-Cache) access primitives: no cache-maintenance ops ----
__device__ __forceinline__ s16x8 ldg_coh(const u16* p) {
    s16x8 r;
    asm volatile("global_load_dwordx4 %0, %1, off sc0 sc1" : "=&v"(r) : "v"(p) : "memory");
    return r;
}
// plain (L2-cacheable) 16B load as volatile asm: cannot be rematerialized -> result
// stays register-resident for the kernel lifetime
__device__ __forceinline__ s16x8 ldg_pin(const u16* p) {
    s16x8 r;
    asm volatile("global_load_dwordx4 %0, %1, off" : "=&v"(r) : "v"(p) : "memory");
    return r;
}
__device__ __forceinline__ void stg_coh32(u16* p, u32 v) {
    asm volatile("global_store_dword %0, %1, off sc0 sc1" :: "v"(p), "v"(v) : "memory");
}
__device__ __forceinline__ u32 ldg_coh_u32(const u32* p) {
    u32 r;
    asm volatile("global_load_dword %0, %1, off sc0 sc1" : "=&v"(r) : "v"(p) : "memory");
    return r;
}
__device__ __forceinline__ void waitvm0() {
    asm volatile("s_waitcnt vmcnt(0)" ::: "memory");
    __builtin_amdgcn_sched_barrier(0);
}

template <int I> struct IC { static constexpr int v = I; };
template <int N, int I = 0, typename F>
__device__ __forceinline__ void sfor(F&& f) {
    if constexpr (I < N) { f(IC<I>{}); sfor<N, I + 1, F>(static_cast<F&&>(f)); }
}

// ---------------- prep: pack weights into per-wave fragment order ----------------
__global__ void prep_kernel(const float* __restrict__ Wx0, const float* __restrict__ Wh0,
                            const float* __restrict__ bx0, const float* __restrict__ bh0,
                            const float* __restrict__ Wx1, const float* __restrict__ Wh1,
                            const float* __restrict__ bx1, const float* __restrict__ bh1,
                            const float* __restrict__ h0in,
                            u16* __restrict__ Wpk0, u16* __restrict__ Wpk1,
                            float* __restrict__ bcomb,
                            u16* __restrict__ h0buf, u16* __restrict__ h1buf,
                            u32* __restrict__ cnt) {
    const long long idx = (long long)blockIdx.x * 256 + threadIdx.x;
    const long long stride = (long long)gridDim.x * 256;
    if (idx < 8) cnt[idx * 16] = 0u;   // 8 counters, 64B apart

    for (long long i = idx; i < 128LL * 4 * 24 * 512; i += stride) {
        const int j = (int)(i & 7);
        const int lane = (int)((i >> 3) & 63);
        const int f = (int)(i >> 9);
        const int nt = f & 1;
        const int q = f >> 1;
        const int c = q % 12, r = q / 12;
        const int wv = r & 3, wg = r >> 2;
        const int pr = lane & 15, lh = lane >> 4;
        const int row = (nt * 2 + (pr >> 3)) * 1024 + wg * 8 + (pr & 7);
        const int k = (c * 4 + wv) * 32 + lh * 8 + j;
        const float v = (k < 512) ? Wx0[(size_t)row * 512 + k] : Wh0[(size_t)row * 1024 + (k - 512)];
        Wpk0[i] = f2bf(v);
    }
    for (long long i = idx; i < 128LL * 4 * 32 * 512; i += stride) {
        const int j = (int)(i & 7);
        const int lane = (int)((i >> 3) & 63);
        const int f = (int)(i >> 9);
        const int nt = f & 1;
        const int q = f >> 1;
        const int c = q & 15, r = q >> 4;
        const int wv = r & 3, wg = r >> 2;
        const int pr = lane & 15, lh = lane >> 4;
        const int row = (nt * 2 + (pr >> 3)) * 1024 + wg * 8 + (pr & 7);
        const int k = (c * 4 + wv) * 32 + lh * 8 + j;
        const float v = (k < 1024) ? Wx1[(size_t)row * 1024 + k] : Wh1[(size_t)row * 1024 + (k - 1024)];
        Wpk1[i] = f2bf(v);
    }
    for (long long i = idx; i < 4096; i += stride) {
        bcomb[i] = bx0[i] + bh0[i];
        bcomb[4096 + i] = bx1[i] + bh1[i];
    }
    // initial h states live in parity-1 slots
    for (long long i = idx; i < BH; i += stride) {
        h0buf[BH + i] = f2bf(h0in[i]);
        h1buf[BH + i] = f2bf(h0in[BH + i]);
    }
}

// ---------------- fence-free bounded grid barrier ----------------
// All threads: drain own wave's coherent stores, then thread0 arrives + polls 8 counters.
__device__ __forceinline__ void gbar(u32* cbase, int slot, u32 tgt, int* sdead) {
    waitvm0();                 // every wave: h stores acked at coherence point
    __syncthreads();
    if (threadIdx.x == 0 && !*sdead) {
        atomicAdd(cbase + slot * 16, 1u);   // relaxed, device-scope: no fence emission
        int guard = 0;
        for (;;) {
            u32 t0 = ldg_coh_u32(cbase + 0 * 16), t1 = ldg_coh_u32(cbase + 1 * 16);
            u32 t2 = ldg_coh_u32(cbase + 2 * 16), t3 = ldg_coh_u32(cbase + 3 * 16);
            u32 t4 = ldg_coh_u32(cbase + 4 * 16), t5 = ldg_coh_u32(cbase + 5 * 16);
            u32 t6 = ldg_coh_u32(cbase + 6 * 16), t7 = ldg_coh_u32(cbase + 7 * 16);
            waitvm0();
            if (t0 + t1 + t2 + t3 + t4 + t5 + t6 + t7 >= tgt) break;
            __builtin_amdgcn_s_sleep(1);
            if (++guard > (1 << 13)) { *sdead = 1; break; }   // ~ms-scale cap, then latch
        }
    }
    __syncthreads();
}

// ---------------- per-layer persistent loop ----------------
// NC = K/128 chunks (L0:12, L1:16); XC = chunks from first A source (L0: x -> 4, L1: h0 -> 8)
template <int NC, int XC, int LAYER>
__device__ __forceinline__ void run_layer(const float* __restrict__ x,
                                          const u16* __restrict__ Wpk,
                                          const float* __restrict__ bias,
                                          const float* __restrict__ c0in,
                                          u16* h0buf, u16* h1buf,
                                          u32* cnt, int wg, int slot, char* smem, int* sdead) {
    const int tid = threadIdx.x;
    const int wid = tid >> 6, lane = tid & 63;
    const int ln15 = lane & 15, lhi = lane >> 4;
    const int col0 = wg * 8;
    short* As = (short*)smem;     // 2 x [64][128] bf16 A-chunk double buffer
    float* Pf = (float*)smem;     // reused: partials [128][67] f32
    const int m_u = tid & 63, cp_u = tid >> 6;

    // register-resident weights: volatile-asm loads cannot be rematerialized,
    // so the fragments stay live in VGPRs for the whole kernel.
    s16x8 wfr[NC * 2];
    const u16* wbase = Wpk + ((size_t)(wg * 4 + wid) * (NC * 2)) * 512 + lane * 8;
    sfor<NC * 2>([&](auto ff) { wfr[ff.v] = ldg_pin(wbase + (size_t)ff.v * 512); });
    waitvm0();

    float bR[4][2];
#pragma unroll
    for (int g = 0; g < 4; ++g) {
        bR[g][0] = bias[g * 1024 + col0 + cp_u * 2 + 0];
        bR[g][1] = bias[g * 1024 + col0 + cp_u * 2 + 1];
    }
    float cr0 = c0in[(size_t)m_u * 1024 + col0 + cp_u * 2 + 0];
    float cr1 = c0in[(size_t)m_u * 1024 + col0 + cp_u * 2 + 1];

    for (int ph = 0; ph <= 512; ++ph) {
        const bool active = (LAYER == 0) ? (ph < 512) : (ph >= 1);
        if (active) {
            const int t = (LAYER == 0) ? ph : ph - 1;
            const u16* hA = h0buf + (size_t)((ph + 1) & 1) * BH;  // L0: h0 prev ; L1: h0 current-t
            const u16* hB = h1buf + (size_t)(ph & 1) * BH;        // L1 only: h1 prev
            u16* hw = (LAYER == 0) ? h0buf + (size_t)(ph & 1) * BH
                                   : h1buf + (size_t)((ph + 1) & 1) * BH;

            // ---- prologue: stage chunk 0 into buffer 0
            {
                float4 xr[4][2]; s16x8 hr[4];
#pragma unroll
                for (int bb = 0; bb < 4; ++bb) {
                    const int blkid = tid + bb * 256, row = blkid >> 4, cb = blkid & 15;
                    const int kg = cb * 8;
                    if constexpr (LAYER == 0) {
                        const float* sp = x + ((size_t)row * Sn + t) * Dn + kg;
                        xr[bb][0] = *(const float4*)sp; xr[bb][1] = *(const float4*)(sp + 4);
                    } else {
                        hr[bb] = ldg_coh(&hA[(size_t)row * Hn + kg]);
                    }
                }
                waitvm0();
#pragma unroll
                for (int bb = 0; bb < 4; ++bb) {
                    const int blkid = tid + bb * 256, row = blkid >> 4, cb = blkid & 15;
                    s16x8 v;
                    if constexpr (LAYER == 0) v = cvt8(xr[bb][0], xr[bb][1]);
                    else v = hr[bb];
                    *(s16x8*)&As[row * 128 + ((cb ^ (row & 7)) * 8)] = v;
                }
            }
            __syncthreads();

            f32x4 acc[4][2];
#pragma unroll
            for (int mi = 0; mi < 4; ++mi) {
                acc[mi][0] = f32x4{0.f, 0.f, 0.f, 0.f};
                acc[mi][1] = f32x4{0.f, 0.f, 0.f, 0.f};
            }

            sfor<NC>([&](auto cc) {
                constexpr int c = cc.v;
                float4 xr[4][2]; s16x8 hr[4];
                // issue next chunk's loads early (latency hides under MFMA)
                if constexpr (c + 1 < NC) {
                    constexpr int cn = c + 1;
#pragma unroll
                    for (int bb = 0; bb < 4; ++bb) {
                        const int blkid = tid + bb * 256, row = blkid >> 4, cb = blkid & 15;
                        const int kg = cn * 128 + cb * 8;
                        if constexpr (LAYER == 0) {
                            if constexpr (cn < XC) {
                                const float* sp = x + ((size_t)row * Sn + t) * Dn + kg;
                                xr[bb][0] = *(const float4*)sp; xr[bb][1] = *(const float4*)(sp + 4);
                            } else {
                                hr[bb] = ldg_coh(&hA[(size_t)row * Hn + (kg - XC * 128)]);
                            }
                        } else {
                            if constexpr (cn < XC) hr[bb] = ldg_coh(&hA[(size_t)row * Hn + kg]);
                            else hr[bb] = ldg_coh(&hB[(size_t)row * Hn + (kg - XC * 128)]);
                        }
                    }
                }
                // compute chunk c: wave wid handles k-slice (c*4 + wid)
                const int ab = (c & 1) * 8192;
#pragma unroll
                for (int mi = 0; mi < 4; ++mi) {
                    const int arow = mi * 16 + ln15;
                    const s16x8 af =
                        *(const s16x8*)&As[ab + arow * 128 + (((wid * 4 + lhi) ^ (arow & 7)) * 8)];
                    acc[mi][0] = __builtin_amdgcn_mfma_f32_16x16x32_bf16(af, wfr[c * 2 + 0], acc[mi][0], 0, 0, 0);
                    acc[mi][1] = __builtin_amdgcn_mfma_f32_16x16x32_bf16(af, wfr[c * 2 + 1], acc[mi][1], 0, 0, 0);
                }
                // write next chunk into the other buffer (after draining its loads)
                if constexpr (c + 1 < NC) {
                    constexpr int cn = c + 1;
                    const int wb = (cn & 1) * 8192;
                    waitvm0();
#pragma unroll
                    for (int bb = 0; bb < 4; ++bb) {
                        const int blkid = tid + bb * 256, row = blkid >> 4, cb = blkid & 15;
                        s16x8 v;
                        if constexpr (LAYER == 0 && (c + 1) < XC) v = cvt8(xr[bb][0], xr[bb][1]);
                        else v = hr[bb];
                        *(s16x8*)&As[wb + row * 128 + ((cb ^ (row & 7)) * 8)] = v;
                    }
                }
                __syncthreads();
            });

            // ---- cross-wave reduction: partial sums -> LDS
#pragma unroll
            for (int mi = 0; mi < 4; ++mi)
#pragma unroll
                for (int nt = 0; nt < 2; ++nt)
#pragma unroll
                    for (int r = 0; r < 4; ++r) {
                        const int m = mi * 16 + lhi * 4 + r;
                        const int g = nt * 2 + (ln15 >> 3), col = ln15 & 7;
                        Pf[(size_t)((wid * 4 + g) * 8 + col) * 67 + m] = acc[mi][nt][r];
                    }
            __syncthreads();

            // ---- fused cell update: thread owns (m_u, cols col0+2cp_u .. +1)
            float sg[4][2];
#pragma unroll
            for (int g = 0; g < 4; ++g) { sg[g][0] = bR[g][0]; sg[g][1] = bR[g][1]; }
#pragma unroll
            for (int wv = 0; wv < 4; ++wv)
#pragma unroll
                for (int g = 0; g < 4; ++g) {
                    sg[g][0] += Pf[(size_t)(wv * 32 + g * 8 + cp_u * 2 + 0) * 67 + m_u];
                    sg[g][1] += Pf[(size_t)(wv * 32 + g * 8 + cp_u * 2 + 1) * 67 + m_u];
                }
            const float i0 = sigmf(sg[0][0]), f0 = sigmf(sg[1][0]), g0 = tanhf(sg[2][0]), o0 = sigmf(sg[3][0]);
            const float i1 = sigmf(sg[0][1]), f1 = sigmf(sg[1][1]), g1 = tanhf(sg[2][1]), o1 = sigmf(sg[3][1]);
            cr0 = f0 * cr0 + i0 * g0;
            cr1 = f1 * cr1 + i1 * g1;
            const u16 hb0 = f2bf(o0 * tanhf(cr0));
            const u16 hb1 = f2bf(o1 * tanhf(cr1));
            stg_coh32(&hw[(size_t)m_u * Hn + col0 + cp_u * 2], (u32)hb0 | ((u32)hb1 << 16));
        }
        if (ph < 512) gbar(cnt, slot, (u32)(ph + 1) * 256u, sdead);
    }
    waitvm0();   // drain final coherent stores before endpgm
}

__global__ __attribute__((amdgpu_flat_work_group_size(256, 256)))
__attribute__((amdgpu_waves_per_eu(1, 1)))
void lstm_persist(const float* __restrict__ x,
                  const u16* __restrict__ Wpk0,
                  const u16* __restrict__ Wpk1,
                  const float* __restrict__ bias,
                  const float* __restrict__ c0in,
                  u16* h0buf, u16* h1buf, u32* cnt) {
    __shared__ __align__(16) char smem[34816];
    __shared__ int sdead;
    if (threadIdx.x == 0) sdead = 0;
    const int slot = blockIdx.x & 7;
    if (blockIdx.x < 128)
        run_layer<12, 4, 0>(x, Wpk0, bias, c0in, h0buf, h1buf, cnt, blockIdx.x, slot, smem, &sdead);
    else
        run_layer<16, 8, 1>(x, Wpk1, bias + 4096, c0in + BH, h0buf, h1buf, cnt, blockIdx.x - 128, slot, smem, &sdead);
}

// ---------------- final FC + sigmoid ----------------
__global__ __launch_bounds__(256) void fc_out(const u16* __restrict__ h1,
                                              const float* __restrict__ fcW,
                                              const float* __restrict__ fcb,
                                              float* __restrict__ out) {
    const int b = blockIdx.x;  // 64
    __shared__ float hs[Hn];
    for (int k = threadIdx.x; k < Hn; k += 256) hs[k] = bf2f(h1[(size_t)b * Hn + k]);
    __syncthreads();
    const int o = threadIdx.x;  // 256
    float acc = fcb[o];
    const float4* wr = (const float4*)(fcW + (size_t)o * Hn);
    const float4* hv = (const float4*)hs;
#pragma unroll 8
    for (int k4 = 0; k4 < Hn / 4; ++k4) {
        const float4 w = wr[k4];
        const float4 h = hv[k4];
        acc += w.x * h.x + w.y * h.y + w.z * h.z + w.w * h.w;
    }
    out[(size_t)b * On + o] = sigmf(acc);
}

extern "C" void kernel_launch(void* const* d_in, const int* in_sizes, int n_in,
                              void* d_out, int out_size, void* d_ws, size_t ws_size,
                              hipStream_t stream) {
    (void)in_sizes; (void)n_in; (void)out_size; (void)ws_size;
    const float* x   = (const float*)d_in[0];
    const float* h0i = (const float*)d_in[1];
    const float* c0i = (const float*)d_in[2];
    const float* Wx0 = (const float*)d_in[3];
    const float* Wh0 = (const float*)d_in[4];
    const float* bx0 = (const float*)d_in[5];
    const float* bh0 = (const float*)d_in[6];
    const float* Wx1 = (const float*)d_in[7];
    const float* Wh1 = (const float*)d_in[8];
    const float* bx1 = (const float*)d_in[9];
    const float* bh1 = (const float*)d_in[10];
    const float* fcW = (const float*)d_in[11];
    const float* fcb = (const float*)d_in[12];
    float* out = (float*)d_out;

    char* ws = (char*)d_ws;
    u16* Wpk0   = (u16*)(ws + 0);            // 12,582,912 B
    u16* Wpk1   = (u16*)(ws + 12582912);     // 16,777,216 B
    float* bias = (float*)(ws + 29360128);   // 32,768 B
    u16* h0buf  = (u16*)(ws + 29392896);     // 262,144 B (2 parity slots)
    u16* h1buf  = (u16*)(ws + 29655040);     // 262,144 B
    u32* cnt    = (u32*)(ws + 29917184);     // 8 counters, 64B apart (512 B)

    prep_kernel<<<2048, 256, 0, stream>>>(Wx0, Wh0, bx0, bh0, Wx1, Wh1, bx1, bh1,
                                          h0i, Wpk0, Wpk1, bias, h0buf, h1buf, cnt);

    lstm_persist<<<256, 256, 0, stream>>>(x, Wpk0, Wpk1, bias, c0i, h0buf, h1buf, cnt);

    fc_out<<<64, 256, 0, stream>>>(h1buf + BH, fcW, fcb, out);
}

// Round 7
// 6813.088 us; speedup vs baseline: 1.0921x; 1.0921x over previous
//
#include <hip/hip_runtime.h>
#include <hip/hip_bf16.h>

// LSTM: B=64, S=512, D=512, H=1024, L=2, O=256
// Persistent kernel, fence-FREE cross-XCD coherence (sc0 sc1 h-path, relaxed-atomic barrier).
// 256 WGs (128/layer, 8 h-cols each). LDS padded to 88KB -> exactly 1 WG/CU, so the
// register allocator gets a 512-VGPR budget and the weight fragments stay resident.

namespace {
constexpr int Bn = 64, Sn = 512, Dn = 512, Hn = 1024, On = 256;
constexpr int BH = Bn * Hn;  // 65536
}

typedef unsigned short u16;
typedef unsigned int u32;
typedef float f32x4 __attribute__((ext_vector_type(4)));
typedef short s16x8 __attribute__((ext_vector_type(8)));
typedef unsigned int u32x4 __attribute__((ext_vector_type(4)));

__device__ __forceinline__ u16 f2bf(float f) {
    unsigned int u = __float_as_uint(f);
    unsigned int r = (u + 0x7fffu + ((u >> 16) & 1u)) >> 16;
    return (u16)r;
}
__device__ __forceinline__ float bf2f(u16 b) {
    return __uint_as_float(((unsigned int)b) << 16);
}
__device__ __forceinline__ float sigmf(float x) { return 1.0f / (1.0f + __expf(-x)); }

__device__ __forceinline__ s16x8 cvt8(const float4 a, const float4 b) {
    s16x8 v;
    v[0] = (short)f2bf(a.x); v[1] = (short)f2bf(a.y); v[2] = (short)f2bf(a.z); v[3] = (short)f2bf(a.w);
    v[4] = (short)f2bf(b.x); v[5] = (short)f2bf(b.y); v[6] = (short)f2bf(b.z); v[7] = (short)f2bf(b.w);
    return v;
}

// ---- coherent (Infinity-Cache) access primitives: no cache-maintenance ops ----
__device__ __forceinline__ s16x8 ldg_coh(const u16* p) {
    s16x8 r;
    asm volatile("global_load_dwordx4 %0, %1, off sc0 sc1" : "=&v"(r) : "v"(p) : "memory");
    return r;
}
// plain (L2-cacheable) 16B load as volatile asm: cannot be rematerialized
__device__ __forceinline__ s16x8 ldg_pin(const u16* p) {
    s16x8 r;
    asm volatile("global_load_dwordx4 %0, %1, off" : "=&v"(r) : "v"(p) : "memory");
    return r;
}
__device__ __forceinline__ void stg_coh128(u16* p, u32x4 v) {
    asm volatile("global_store_dwordx4 %0, %1, off sc0 sc1" :: "v"(p), "v"(v) : "memory");
}
__device__ __forceinline__ u32 ldg_coh_u32(const u32* p) {
    u32 r;
    asm volatile("global_load_dword %0, %1, off sc0 sc1" : "=&v"(r) : "v"(p) : "memory");
    return r;
}
__device__ __forceinline__ void waitvm0() {
    asm volatile("s_waitcnt vmcnt(0)" ::: "memory");
    __builtin_amdgcn_sched_barrier(0);
}

template <int I> struct IC { static constexpr int v = I; };
template <int N, int I = 0, typename F>
__device__ __forceinline__ void sfor(F&& f) {
    if constexpr (I < N) { f(IC<I>{}); sfor<N, I + 1, F>(static_cast<F&&>(f)); }
}

// ---------------- prep: pack weights into per-wave fragment order ----------------
__global__ void prep_kernel(const float* __restrict__ Wx0, const float* __restrict__ Wh0,
                            const float* __restrict__ bx0, const float* __restrict__ bh0,
                            const float* __restrict__ Wx1, const float* __restrict__ Wh1,
                            const float* __restrict__ bx1, const float* __restrict__ bh1,
                            const float* __restrict__ h0in,
                            u16* __restrict__ Wpk0, u16* __restrict__ Wpk1,
                            float* __restrict__ bcomb,
                            u16* __restrict__ h0buf, u16* __restrict__ h1buf,
                            u32* __restrict__ cnt) {
    const long long idx = (long long)blockIdx.x * 256 + threadIdx.x;
    const long long stride = (long long)gridDim.x * 256;
    if (idx < 8) cnt[idx * 16] = 0u;   // 8 counters, 64B apart

    for (long long i = idx; i < 128LL * 4 * 24 * 512; i += stride) {
        const int j = (int)(i & 7);
        const int lane = (int)((i >> 3) & 63);
        const int f = (int)(i >> 9);
        const int nt = f & 1;
        const int q = f >> 1;
        const int c = q % 12, r = q / 12;
        const int wv = r & 3, wg = r >> 2;
        const int pr = lane & 15, lh = lane >> 4;
        const int row = (nt * 2 + (pr >> 3)) * 1024 + wg * 8 + (pr & 7);
        const int k = (c * 4 + wv) * 32 + lh * 8 + j;
        const float v = (k < 512) ? Wx0[(size_t)row * 512 + k] : Wh0[(size_t)row * 1024 + (k - 512)];
        Wpk0[i] = f2bf(v);
    }
    for (long long i = idx; i < 128LL * 4 * 32 * 512; i += stride) {
        const int j = (int)(i & 7);
        const int lane = (int)((i >> 3) & 63);
        const int f = (int)(i >> 9);
        const int nt = f & 1;
        const int q = f >> 1;
        const int c = q & 15, r = q >> 4;
        const int wv = r & 3, wg = r >> 2;
        const int pr = lane & 15, lh = lane >> 4;
        const int row = (nt * 2 + (pr >> 3)) * 1024 + wg * 8 + (pr & 7);
        const int k = (c * 4 + wv) * 32 + lh * 8 + j;
        const float v = (k < 1024) ? Wx1[(size_t)row * 1024 + k] : Wh1[(size_t)row * 1024 + (k - 1024)];
        Wpk1[i] = f2bf(v);
    }
    for (long long i = idx; i < 4096; i += stride) {
        bcomb[i] = bx0[i] + bh0[i];
        bcomb[4096 + i] = bx1[i] + bh1[i];
    }
    // initial h states live in parity-1 slots
    for (long long i = idx; i < BH; i += stride) {
        h0buf[BH + i] = f2bf(h0in[i]);
        h1buf[BH + i] = f2bf(h0in[BH + i]);
    }
}

// ---------------- fence-free bounded grid barrier ----------------
__device__ __forceinline__ void gbar(u32* cbase, int slot, u32 tgt, int* sdead) {
    waitvm0();                 // every wave: coherent stores acked
    __syncthreads();
    if (threadIdx.x == 0 && !*sdead) {
        atomicAdd(cbase + slot * 16, 1u);   // relaxed, device-scope: no fence emission
        int guard = 0;
        for (;;) {
            u32 t0 = ldg_coh_u32(cbase + 0 * 16), t1 = ldg_coh_u32(cbase + 1 * 16);
            u32 t2 = ldg_coh_u32(cbase + 2 * 16), t3 = ldg_coh_u32(cbase + 3 * 16);
            u32 t4 = ldg_coh_u32(cbase + 4 * 16), t5 = ldg_coh_u32(cbase + 5 * 16);
            u32 t6 = ldg_coh_u32(cbase + 6 * 16), t7 = ldg_coh_u32(cbase + 7 * 16);
            waitvm0();
            if (t0 + t1 + t2 + t3 + t4 + t5 + t6 + t7 >= tgt) break;
            __builtin_amdgcn_s_sleep(1);
            if (++guard > (1 << 13)) { *sdead = 1; break; }   // bounded, then latch
        }
    }
    __syncthreads();
}

// ---------------- per-layer persistent loop ----------------
// NC = K/128 chunks (L0:12, L1:16); XC = chunks from first A source (L0: x -> 4, L1: h0 -> 8)
template <int NC, int XC, int LAYER>
__device__ __forceinline__ void run_layer(const float* __restrict__ x,
                                          const u16* __restrict__ Wpk,
                                          const float* __restrict__ bias,
                                          const float* __restrict__ c0in,
                                          u16* h0buf, u16* h1buf,
                                          u32* cnt, int wg, int slot, char* smem, int* sdead) {
    const int tid = threadIdx.x;
    const int wid = tid >> 6, lane = tid & 63;
    const int ln15 = lane & 15, lhi = lane >> 4;
    const int col0 = wg * 8;
    short* As = (short*)smem;                 // 2 x [64][128] bf16 A-chunk double buffer
    float* Pf = (float*)smem;                 // reused: partials [128][67] f32 (34304 B)
    u32* hstg = (u32*)(smem + 36864);         // h-store staging [64 rows][4 u32] (1 KB)
    const int m_u = tid & 63, cp_u = tid >> 6;

    // register-resident weights: volatile-asm loads can't be rematerialized; with 1 WG/CU
    // the allocator has a 512-VGPR budget, so these stay in registers.
    s16x8 wfr[NC * 2];
    const u16* wbase = Wpk + ((size_t)(wg * 4 + wid) * (NC * 2)) * 512 + lane * 8;
    sfor<NC * 2>([&](auto ff) { wfr[ff.v] = ldg_pin(wbase + (size_t)ff.v * 512); });
    waitvm0();

    float bR[4][2];
#pragma unroll
    for (int g = 0; g < 4; ++g) {
        bR[g][0] = bias[g * 1024 + col0 + cp_u * 2 + 0];
        bR[g][1] = bias[g * 1024 + col0 + cp_u * 2 + 1];
    }
    float cr0 = c0in[(size_t)m_u * 1024 + col0 + cp_u * 2 + 0];
    float cr1 = c0in[(size_t)m_u * 1024 + col0 + cp_u * 2 + 1];

    for (int ph = 0; ph <= 512; ++ph) {
        const bool active = (LAYER == 0) ? (ph < 512) : (ph >= 1);
        if (active) {
            const int t = (LAYER == 0) ? ph : ph - 1;
            const u16* hA = h0buf + (size_t)((ph + 1) & 1) * BH;  // L0: h0 prev ; L1: h0 current-t
            const u16* hB = h1buf + (size_t)(ph & 1) * BH;        // L1 only: h1 prev
            u16* hw = (LAYER == 0) ? h0buf + (size_t)(ph & 1) * BH
                                   : h1buf + (size_t)((ph + 1) & 1) * BH;

            // ---- prologue: stage chunk 0 into buffer 0
            {
                float4 xr[4][2]; s16x8 hr[4];
#pragma unroll
                for (int bb = 0; bb < 4; ++bb) {
                    const int blkid = tid + bb * 256, row = blkid >> 4, cb = blkid & 15;
                    const int kg = cb * 8;
                    if constexpr (LAYER == 0) {
                        const float* sp = x + ((size_t)row * Sn + t) * Dn + kg;
                        xr[bb][0] = *(const float4*)sp; xr[bb][1] = *(const float4*)(sp + 4);
                    } else {
                        hr[bb] = ldg_coh(&hA[(size_t)row * Hn + kg]);
                    }
                }
                waitvm0();
#pragma unroll
                for (int bb = 0; bb < 4; ++bb) {
                    const int blkid = tid + bb * 256, row = blkid >> 4, cb = blkid & 15;
                    s16x8 v;
                    if constexpr (LAYER == 0) v = cvt8(xr[bb][0], xr[bb][1]);
                    else v = hr[bb];
                    *(s16x8*)&As[row * 128 + ((cb ^ (row & 7)) * 8)] = v;
                }
            }
            __syncthreads();

            f32x4 acc[4][2];
#pragma unroll
            for (int mi = 0; mi < 4; ++mi) {
                acc[mi][0] = f32x4{0.f, 0.f, 0.f, 0.f};
                acc[mi][1] = f32x4{0.f, 0.f, 0.f, 0.f};
            }

            sfor<NC>([&](auto cc) {
                constexpr int c = cc.v;
                float4 xr[4][2]; s16x8 hr[4];
                // issue next chunk's loads early (latency hides under MFMA)
                if constexpr (c + 1 < NC) {
                    constexpr int cn = c + 1;
#pragma unroll
                    for (int bb = 0; bb < 4; ++bb) {
                        const int blkid = tid + bb * 256, row = blkid >> 4, cb = blkid & 15;
                        const int kg = cn * 128 + cb * 8;
                        if constexpr (LAYER == 0) {
                            if constexpr (cn < XC) {
                                const float* sp = x + ((size_t)row * Sn + t) * Dn + kg;
                                xr[bb][0] = *(const float4*)sp; xr[bb][1] = *(const float4*)(sp + 4);
                            } else {
                                hr[bb] = ldg_coh(&hA[(size_t)row * Hn + (kg - XC * 128)]);
                            }
                        } else {
                            if constexpr (cn < XC) hr[bb] = ldg_coh(&hA[(size_t)row * Hn + kg]);
                            else hr[bb] = ldg_coh(&hB[(size_t)row * Hn + (kg - XC * 128)]);
                        }
                    }
                }
                // compute chunk c: wave wid handles k-slice (c*4 + wid)
                const int ab = (c & 1) * 8192;
#pragma unroll
                for (int mi = 0; mi < 4; ++mi) {
                    const int arow = mi * 16 + ln15;
                    const s16x8 af =
                        *(const s16x8*)&As[ab + arow * 128 + (((wid * 4 + lhi) ^ (arow & 7)) * 8)];
                    acc[mi][0] = __builtin_amdgcn_mfma_f32_16x16x32_bf16(af, wfr[c * 2 + 0], acc[mi][0], 0, 0, 0);
                    acc[mi][1] = __builtin_amdgcn_mfma_f32_16x16x32_bf16(af, wfr[c * 2 + 1], acc[mi][1], 0, 0, 0);
                }
                // write next chunk into the other buffer (after draining its loads)
                if constexpr (c + 1 < NC) {
                    constexpr int cn = c + 1;
                    const int wb = (cn & 1) * 8192;
                    waitvm0();
#pragma unroll
                    for (int bb = 0; bb < 4; ++bb) {
                        const int blkid = tid + bb * 256, row = blkid >> 4, cb = blkid & 15;
                        s16x8 v;
                        if constexpr (LAYER == 0 && (c + 1) < XC) v = cvt8(xr[bb][0], xr[bb][1]);
                        else v = hr[bb];
                        *(s16x8*)&As[wb + row * 128 + ((cb ^ (row & 7)) * 8)] = v;
                    }
                }
                __syncthreads();
            });

            // ---- cross-wave reduction: partial sums -> LDS
#pragma unroll
            for (int mi = 0; mi < 4; ++mi)
#pragma unroll
                for (int nt = 0; nt < 2; ++nt)
#pragma unroll
                    for (int r = 0; r < 4; ++r) {
                        const int m = mi * 16 + lhi * 4 + r;
                        const int g = nt * 2 + (ln15 >> 3), col = ln15 & 7;
                        Pf[(size_t)((wid * 4 + g) * 8 + col) * 67 + m] = acc[mi][nt][r];
                    }
            __syncthreads();

            // ---- fused cell update: thread owns (m_u, cols col0+2cp_u .. +1)
            float sg[4][2];
#pragma unroll
            for (int g = 0; g < 4; ++g) { sg[g][0] = bR[g][0]; sg[g][1] = bR[g][1]; }
#pragma unroll
            for (int wv = 0; wv < 4; ++wv)
#pragma unroll
                for (int g = 0; g < 4; ++g) {
                    sg[g][0] += Pf[(size_t)(wv * 32 + g * 8 + cp_u * 2 + 0) * 67 + m_u];
                    sg[g][1] += Pf[(size_t)(wv * 32 + g * 8 + cp_u * 2 + 1) * 67 + m_u];
                }
            const float i0 = sigmf(sg[0][0]), f0 = sigmf(sg[1][0]), g0 = tanhf(sg[2][0]), o0 = sigmf(sg[3][0]);
            const float i1 = sigmf(sg[0][1]), f1 = sigmf(sg[1][1]), g1 = tanhf(sg[2][1]), o1 = sigmf(sg[3][1]);
            cr0 = f0 * cr0 + i0 * g0;
            cr1 = f1 * cr1 + i1 * g1;
            const u16 hb0 = f2bf(o0 * tanhf(cr0));
            const u16 hb1 = f2bf(o1 * tanhf(cr1));
            // stage h in LDS, then wave 0 does one coherent 16B store per row (coalesced)
            hstg[m_u * 4 + cp_u] = (u32)hb0 | ((u32)hb1 << 16);
            __syncthreads();
            if (tid < 64) {
                u32x4 hv;
                hv[0] = hstg[tid * 4 + 0]; hv[1] = hstg[tid * 4 + 1];
                hv[2] = hstg[tid * 4 + 2]; hv[3] = hstg[tid * 4 + 3];
                stg_coh128(&hw[(size_t)tid * Hn + col0], hv);
            }
        }
        if (ph < 512) gbar(cnt, slot, (u32)(ph + 1) * 256u, sdead);
    }
    waitvm0();   // drain final coherent stores before endpgm
}

__global__ __attribute__((amdgpu_flat_work_group_size(256, 256)))
__attribute__((amdgpu_waves_per_eu(1, 1)))
void lstm_persist(const float* __restrict__ x,
                  const u16* __restrict__ Wpk0,
                  const u16* __restrict__ Wpk1,
                  const float* __restrict__ bias,
                  const float* __restrict__ c0in,
                  u16* h0buf, u16* h1buf, u32* cnt) {
    // 88 KB LDS: only ~37 KB used, padded so exactly 1 WG fits per CU. This (a) gives the
    // register allocator a 512-VGPR budget (no weight spill) and (b) forces the dispatcher
    // to spread the 256 WGs across all 256 CUs.
    __shared__ __align__(16) char smem[90112];
    __shared__ int sdead;
    if (threadIdx.x == 0) sdead = 0;
    const int slot = blockIdx.x & 7;
    if (blockIdx.x < 128)
        run_layer<12, 4, 0>(x, Wpk0, bias, c0in, h0buf, h1buf, cnt, blockIdx.x, slot, smem, &sdead);
    else
        run_layer<16, 8, 1>(x, Wpk1, bias + 4096, c0in + BH, h0buf, h1buf, cnt, blockIdx.x - 128, slot, smem, &sdead);
}

// ---------------- final FC + sigmoid ----------------
__global__ __launch_bounds__(256) void fc_out(const u16* __restrict__ h1,
                                              const float* __restrict__ fcW,
                                              const float* __restrict__ fcb,
                                              float* __restrict__ out) {
    const int b = blockIdx.x;  // 64
    __shared__ float hs[Hn];
    for (int k = threadIdx.x; k < Hn; k += 256) hs[k] = bf2f(h1[(size_t)b * Hn + k]);
    __syncthreads();
    const int o = threadIdx.x;  // 256
    float acc = fcb[o];
    const float4* wr = (const float4*)(fcW + (size_t)o * Hn);
    const float4* hv = (const float4*)hs;
#pragma unroll 8
    for (int k4 = 0; k4 < Hn / 4; ++k4) {
        const float4 w = wr[k4];
        const float4 h = hv[k4];
        acc += w.x * h.x + w.y * h.y + w.z * h.z + w.w * h.w;
    }
    out[(size_t)b * On + o] = sigmf(acc);
}

extern "C" void kernel_launch(void* const* d_in, const int* in_sizes, int n_in,
                              void* d_out, int out_size, void* d_ws, size_t ws_size,
                              hipStream_t stream) {
    (void)in_sizes; (void)n_in; (void)out_size; (void)ws_size;
    const float* x   = (const float*)d_in[0];
    const float* h0i = (const float*)d_in[1];
    const float* c0i = (const float*)d_in[2];
    const float* Wx0 = (const float*)d_in[3];
    const float* Wh0 = (const float*)d_in[4];
    const float* bx0 = (const float*)d_in[5];
    const float* bh0 = (const float*)d_in[6];
    const float* Wx1 = (const float*)d_in[7];
    const float* Wh1 = (const float*)d_in[8];
    const float* bx1 = (const float*)d_in[9];
    const float* bh1 = (const float*)d_in[10];
    const float* fcW = (const float*)d_in[11];
    const float* fcb = (const float*)d_in[12];
    float* out = (float*)d_out;

    char* ws = (char*)d_ws;
    u16* Wpk0   = (u16*)(ws + 0);            // 12,582,912 B
    u16* Wpk1   = (u16*)(ws + 12582912);     // 16,777,216 B
    float* bias = (float*)(ws + 29360128);   // 32,768 B
    u16* h0buf  = (u16*)(ws + 29392896);     // 262,144 B (2 parity slots)
    u16* h1buf  = (u16*)(ws + 29655040);     // 262,144 B
    u32* cnt    = (u32*)(ws + 29917184);     // 8 counters, 64B apart (512 B)

    prep_kernel<<<2048, 256, 0, stream>>>(Wx0, Wh0, bx0, bh0, Wx1, Wh1, bx1, bh1,
                                          h0i, Wpk0, Wpk1, bias, h0buf, h1buf, cnt);

    lstm_persist<<<256, 256, 0, stream>>>(x, Wpk0, Wpk1, bias, c0i, h0buf, h1buf, cnt);

    fc_out<<<64, 256, 0, stream>>>(h1buf + BH, fcW, fcb, out);
}